// Round 1
// baseline (183.171 us; speedup 1.0000x reference)
//
#include <hip/hip_runtime.h>
#include <hip/hip_bf16.h>

#define NB 16
#define C 256
#define C4 64
#define HDIM 128
#define WDIM 128
#define HW 16384

typedef __bf16 bf16x8 __attribute__((ext_vector_type(8)));
typedef float f32x4 __attribute__((ext_vector_type(4)));

__device__ __forceinline__ unsigned short f2bf(float x) {
    union { float f; unsigned u; } a; a.f = x;
    unsigned r = a.u + 0x7FFF + ((a.u >> 16) & 1);   // round-to-nearest-even
    return (unsigned short)(r >> 16);
}
__device__ __forceinline__ float bf2f(unsigned short b) {
    union { float f; unsigned u; } a; a.u = ((unsigned)b) << 16; return a.f;
}

// ---------------------------------------------------------------------------
// K0: pack conv_w (64x256) and fuse_w (256x64) into MFMA A-fragment order,
// and compute fuse_b_eff[c] = fuse_b[c] + sum_o fuse_w[c][o]*dw_b[o].
// A-fragment (16x16x32): lane = (m&15) | (((k>>3)&3)<<4), e = k&7.
// frag index = (m>>4)*(K/32) + (k>>5). Each frag = 64 lanes * 8 bf16 = 1 KiB.
// ---------------------------------------------------------------------------
__global__ __launch_bounds__(256) void k0_pack(
    const float* __restrict__ conv_w, const float* __restrict__ fuse_w,
    const float* __restrict__ fuse_b, const float* __restrict__ dw_b,
    unsigned short* __restrict__ cwpk, unsigned short* __restrict__ fwpk,
    float* __restrict__ fbe)
{
    int tid = blockIdx.x * 256 + threadIdx.x;   // 0..16383
    {   // conv_w: M=64, K=256
        int m = tid >> 8, k = tid & 255;
        int frag = (m >> 4) * 8 + (k >> 5);
        int lane = (m & 15) | (((k >> 3) & 3) << 4);
        int e = k & 7;
        cwpk[(frag * 64 + lane) * 8 + e] = f2bf(conv_w[m * 256 + k]);
    }
    {   // fuse_w: M=256, K=64
        int m = tid >> 6, k = tid & 63;
        int frag = (m >> 4) * 2 + (k >> 5);
        int lane = (m & 15) | (((k >> 3) & 3) << 4);
        int e = k & 7;
        fwpk[(frag * 64 + lane) * 8 + e] = f2bf(fuse_w[m * 64 + k]);
    }
    if (tid < 256) {
        float s = fuse_b[tid];
        #pragma unroll
        for (int o = 0; o < 64; ++o) s += fuse_w[tid * 64 + o] * dw_b[o];
        fbe[tid] = s;
    }
}

// ---------------------------------------------------------------------------
// K1: f = conv1(x) + conv_b   (GEMM: M=64 o, N=pixels, K=256 c), f -> bf16 ws.
// Block: 64 pixels x 64 out-channels. 4 waves, wave w owns pixels [16w,16w+16).
// ---------------------------------------------------------------------------
__global__ __launch_bounds__(256) void k1_conv(
    const float* __restrict__ x, const unsigned short* __restrict__ cwpk,
    const float* __restrict__ conv_b, unsigned short* __restrict__ f_ws)
{
    int tile = blockIdx.x;                // 4096 tiles
    int n = tile >> 8;
    int p0 = (tile & 255) * 64;
    int lane = threadIdx.x & 63, wv = threadIdx.x >> 6;
    int gq = lane >> 4;
    int prow = p0 + wv * 16 + (lane & 15);
    const float* xn = x + (size_t)n * C * HW;

    f32x4 acc[4] = {{0.f,0.f,0.f,0.f},{0.f,0.f,0.f,0.f},
                    {0.f,0.f,0.f,0.f},{0.f,0.f,0.f,0.f}};
    for (int kc = 0; kc < 8; ++kc) {
        int cb = kc * 32 + gq * 8;
        union { bf16x8 v; unsigned short u[8]; } b;
        #pragma unroll
        for (int e = 0; e < 8; ++e)
            b.u[e] = f2bf(xn[(size_t)(cb + e) * HW + prow]);
        #pragma unroll
        for (int m = 0; m < 4; ++m) {
            bf16x8 a = *reinterpret_cast<const bf16x8*>(cwpk + ((m * 8 + kc) * 64 + lane) * 8);
            acc[m] = __builtin_amdgcn_mfma_f32_16x16x32_bf16(a, b.v, acc[m], 0, 0, 0);
        }
    }
    unsigned short* fn = f_ws + (size_t)n * C4 * HW;
    #pragma unroll
    for (int m = 0; m < 4; ++m) {
        #pragma unroll
        for (int e = 0; e < 4; ++e) {
            int o = m * 16 + gq * 4 + e;               // D row = 4*(lane>>4)+reg
            fn[(size_t)o * HW + prow] = f2bf(acc[m][e] + conv_b[o]);
        }
    }
}

// ---------------------------------------------------------------------------
// K2: g[n,o,i,j] = mean of f over torch-adaptive bins.
// H=W=128, k=3: bins [0,43),[42,86),[85,128)  (row 42 & 85 in TWO bins).
// One block per (n,o) plane.
// ---------------------------------------------------------------------------
__global__ __launch_bounds__(256) void k2_pool(
    const unsigned short* __restrict__ f_ws, float* __restrict__ g_ws)
{
    int no = blockIdx.x;                                  // 0..1023
    const unsigned short* fp = f_ws + (size_t)no * HW;
    int tid = threadIdx.x;
    float s[9];
    #pragma unroll
    for (int k = 0; k < 9; ++k) s[k] = 0.f;

    for (int it = 0; it < 8; ++it) {
        int p = (it * 256 + tid) * 8;                     // 8 bf16 per iter
        int h = p >> 7, wbase = p & 127;
        union { uint4 q; unsigned short u[8]; } d;
        d.q = *reinterpret_cast<const uint4*>(fp + p);
        float cs0 = 0.f, cs1 = 0.f, cs2 = 0.f;            // per-col-bin sums
        #pragma unroll
        for (int z = 0; z < 8; ++z) {
            float v = bf2f(d.u[z]);
            int w = wbase + z;
            if (w < 43)            cs0 += v;
            if (w >= 42 && w < 86) cs1 += v;
            if (w >= 85)           cs2 += v;
        }
        if (h < 43)            { s[0] += cs0; s[1] += cs1; s[2] += cs2; }
        if (h >= 42 && h < 86) { s[3] += cs0; s[4] += cs1; s[5] += cs2; }
        if (h >= 85)           { s[6] += cs0; s[7] += cs1; s[8] += cs2; }
    }

    __shared__ float red[4][9];
    int lane = tid & 63, wv = tid >> 6;
    #pragma unroll
    for (int k = 0; k < 9; ++k) {
        float v = s[k];
        for (int off = 32; off > 0; off >>= 1) v += __shfl_down(v, off, 64);
        s[k] = v;
    }
    if (lane == 0) {
        #pragma unroll
        for (int k = 0; k < 9; ++k) red[wv][k] = s[k];
    }
    __syncthreads();
    if (tid < 9) {
        const int cnt[3] = {43, 44, 43};
        float tot = red[0][tid] + red[1][tid] + red[2][tid] + red[3][tid];
        int i = tid / 3, j = tid - 3 * i;
        g_ws[no * 9 + tid] = tot / (float)(cnt[i] * cnt[j]);
    }
}

// ---------------------------------------------------------------------------
// K3: y = depthwise3x3(f, g) ; out = fuse_w . y + fuse_b_eff
// Block: one n, one row h, 64-col tile. y (64o x 64p) staged bf16 in LDS
// (stride 66 -> conflict-free fragment reads), then MFMA K=64 -> 256 channels.
// ---------------------------------------------------------------------------
__global__ __launch_bounds__(256) void k3_dwfuse(
    const unsigned short* __restrict__ f_ws, const float* __restrict__ g_ws,
    const unsigned short* __restrict__ fwpk, const float* __restrict__ fbe,
    float* __restrict__ out)
{
    __shared__ unsigned short ylds[64][66];
    int blk = blockIdx.x;                 // 4096
    int n = blk >> 8;
    int h = (blk >> 1) & 127;
    int wt = blk & 1;
    int w0 = wt * 64;
    int t = threadIdx.x;

    {   // depthwise: thread t -> channel o = t>>2, 16 pixels (quarter q)
        int o = t >> 2, q = t & 3;
        const unsigned short* fp = f_ws + (size_t)(n * 64 + o) * HW;
        const float* gp = g_ws + (n * 64 + o) * 9;
        float gv[9];
        #pragma unroll
        for (int k = 0; k < 9; ++k) gv[k] = gp[k];
        int wb = w0 + q * 16;
        float y[16];
        #pragma unroll
        for (int i = 0; i < 16; ++i) y[i] = 0.f;
        #pragma unroll
        for (int dy = -1; dy <= 1; ++dy) {
            int hh = h + dy;
            if (hh < 0 || hh >= HDIM) continue;
            const unsigned short* row = fp + hh * WDIM;
            float rv[18];
            #pragma unroll
            for (int k = 0; k < 18; ++k) {
                int ww = wb - 1 + k;
                rv[k] = (ww >= 0 && ww < WDIM) ? bf2f(row[ww]) : 0.f;
            }
            float g0 = gv[(dy + 1) * 3], g1 = gv[(dy + 1) * 3 + 1], g2 = gv[(dy + 1) * 3 + 2];
            #pragma unroll
            for (int i = 0; i < 16; ++i)
                y[i] += g0 * rv[i] + g1 * rv[i + 1] + g2 * rv[i + 2];
        }
        union { unsigned int d[8]; unsigned short u[16]; } pk;
        #pragma unroll
        for (int i = 0; i < 16; ++i) pk.u[i] = f2bf(y[i]);
        unsigned int* dst = reinterpret_cast<unsigned int*>(&ylds[o][q * 16]);
        #pragma unroll
        for (int i = 0; i < 8; ++i) dst[i] = pk.d[i];
    }
    __syncthreads();

    int lane = t & 63, wv = t >> 6, gq = lane >> 4;
    f32x4 acc[4][4];
    #pragma unroll
    for (int a = 0; a < 4; ++a)
        #pragma unroll
        for (int b = 0; b < 4; ++b) acc[a][b] = (f32x4){0.f,0.f,0.f,0.f};

    #pragma unroll
    for (int kc = 0; kc < 2; ++kc) {
        bf16x8 bfr[4];
        #pragma unroll
        for (int pj = 0; pj < 4; ++pj) {
            union { bf16x8 v; unsigned short u[8]; } bb;
            #pragma unroll
            for (int e = 0; e < 8; ++e)
                bb.u[e] = ylds[kc * 32 + gq * 8 + e][pj * 16 + (lane & 15)];
            bfr[pj] = bb.v;
        }
        #pragma unroll
        for (int mc = 0; mc < 4; ++mc) {
            bf16x8 a = *reinterpret_cast<const bf16x8*>(
                fwpk + (((wv * 4 + mc) * 2 + kc) * 64 + lane) * 8);
            #pragma unroll
            for (int pj = 0; pj < 4; ++pj)
                acc[mc][pj] = __builtin_amdgcn_mfma_f32_16x16x32_bf16(a, bfr[pj], acc[mc][pj], 0, 0, 0);
        }
    }

    size_t outbase = (size_t)n * C * HW + (size_t)h * WDIM + w0;
    #pragma unroll
    for (int mc = 0; mc < 4; ++mc) {
        #pragma unroll
        for (int e = 0; e < 4; ++e) {
            int c = wv * 64 + mc * 16 + gq * 4 + e;
            float bias = fbe[c];
            #pragma unroll
            for (int pj = 0; pj < 4; ++pj) {
                int w = pj * 16 + (lane & 15);
                out[outbase + (size_t)c * HW + w] = acc[mc][pj][e] + bias;
            }
        }
    }
}

// ---------------------------------------------------------------------------
extern "C" void kernel_launch(void* const* d_in, const int* in_sizes, int n_in,
                              void* d_out, int out_size, void* d_ws, size_t ws_size,
                              hipStream_t stream) {
    const float* x      = (const float*)d_in[0];
    const float* conv_w = (const float*)d_in[1];
    const float* conv_b = (const float*)d_in[2];
    const float* dw_b   = (const float*)d_in[3];
    const float* fuse_w = (const float*)d_in[4];
    const float* fuse_b = (const float*)d_in[5];
    float* out = (float*)d_out;

    char* ws = (char*)d_ws;
    unsigned short* f_ws = (unsigned short*)ws;                       // 32 MiB
    float* g_ws          = (float*)(ws + 33554432);                   // 36 KiB
    unsigned short* cwpk = (unsigned short*)(ws + 33554432 + 36864);  // 32 KiB
    unsigned short* fwpk = (unsigned short*)(ws + 33554432 + 36864 + 32768);
    float* fbe           = (float*)(ws + 33554432 + 36864 + 32768 + 32768);

    k0_pack<<<dim3(64), dim3(256), 0, stream>>>(conv_w, fuse_w, fuse_b, dw_b, cwpk, fwpk, fbe);
    k1_conv<<<dim3(4096), dim3(256), 0, stream>>>(x, cwpk, conv_b, f_ws);
    k2_pool<<<dim3(1024), dim3(256), 0, stream>>>(f_ws, g_ws);
    k3_dwfuse<<<dim3(4096), dim3(256), 0, stream>>>(f_ws, g_ws, fwpk, fbe, out);
}